// Round 1
// baseline (242.704 us; speedup 1.0000x reference)
//
#include <hip/hip_runtime.h>

constexpr int NN   = 10000;   // nodes
constexpr int INF  = 50;      // in feats
constexpr int HID  = 512;     // hidden
constexpr int OUTF = 121;     // out feats
constexpr int NE   = 160000;  // edges

// ---------------- CSR build ----------------

__global__ __launch_bounds__(256) void k_count(const int* __restrict__ dstv, int* __restrict__ deg) {
    int e = blockIdx.x * 256 + threadIdx.x;
    if (e < NE) {
        int d = dstv[e];
        if ((unsigned)d < (unsigned)NN) atomicAdd(&deg[d], 1);
    }
}

__global__ __launch_bounds__(256) void k_scan(const int* __restrict__ deg, int* __restrict__ offs) {
    __shared__ int sums[256];
    int t = threadIdx.x;
    int start = t * 40;
    int end = min(start + 40, NN);
    int s = 0;
    for (int i = start; i < end; ++i) s += deg[i];
    sums[t] = s;
    __syncthreads();
    if (t == 0) {
        int run = 0;
        for (int i = 0; i < 256; ++i) { int v = sums[i]; sums[i] = run; run += v; }
        offs[NN] = run;
    }
    __syncthreads();
    int b = sums[t];
    for (int i = start; i < end; ++i) { offs[i] = b; b += deg[i]; }
}

__global__ __launch_bounds__(256) void k_fill(const int* __restrict__ srcv, const int* __restrict__ dstv,
                                              const int* __restrict__ offs, int* __restrict__ cursor,
                                              int* __restrict__ csr) {
    int e = blockIdx.x * 256 + threadIdx.x;
    if (e < NE) {
        int d = dstv[e];
        if ((unsigned)d < (unsigned)NN) {
            int pos = atomicAdd(&cursor[d], 1);
            csr[offs[d] + pos] = srcv[e];
        }
    }
}

// ---------------- Layer 1: aggregate x (50 feats), build A1 = [agg | x] [NN,100] ----------------

__global__ __launch_bounds__(64) void k_agg1(const float* __restrict__ x, const int* __restrict__ offs,
                                             const int* __restrict__ csr, float* __restrict__ A1) {
    int n = blockIdx.x;
    int f = threadIdx.x;
    int b0 = offs[n], b1 = offs[n + 1];
    if (f < INF) {
        float s = 0.f;
        for (int i = b0; i < b1; ++i) {
            int sn = csr[i];
            s += x[sn * INF + f];
        }
        int dg = b1 - b0;
        float invd = dg > 0 ? 1.f / (float)dg : 1.f;
        A1[n * 100 + f] = s * invd;
        A1[n * 100 + INF + f] = x[n * INF + f];
    }
}

// ---------------- GEMM1: h = relu(A1[:, :50] @ W1l + A1[:, 50:] @ W1r + b1)  [NN,512] ----------------
// 32 rows x 128 cols per block, 4x4 register tile per thread, K=100 fully staged in LDS (transposed).

__global__ __launch_bounds__(256) void k_gemm1(const float* __restrict__ A1, const float* __restrict__ Wl,
                                               const float* __restrict__ Wr, const float* __restrict__ bias,
                                               float* __restrict__ h) {
    __shared__ __align__(16) float As[100 * 36];
    int t = threadIdx.x;
    int m0 = blockIdx.x * 32;
    int n0 = blockIdx.y * 128;
    for (int idx = t; idx < 3200; idx += 256) {
        int row = idx / 100, k = idx - row * 100;
        int node = m0 + row;
        As[k * 36 + row] = node < NN ? A1[node * 100 + k] : 0.f;
    }
    __syncthreads();
    int c0 = (t & 31) * 4, r0 = (t >> 5) * 4;
    float acc[4][4] = {};
#pragma unroll 2
    for (int k = 0; k < 50; ++k) {
        float4 a = *(const float4*)&As[k * 36 + r0];
        float4 w = *(const float4*)&Wl[k * HID + n0 + c0];
        float av[4] = {a.x, a.y, a.z, a.w};
        float wv[4] = {w.x, w.y, w.z, w.w};
#pragma unroll
        for (int i = 0; i < 4; ++i)
#pragma unroll
            for (int j = 0; j < 4; ++j) acc[i][j] += av[i] * wv[j];
    }
#pragma unroll 2
    for (int k = 0; k < 50; ++k) {
        float4 a = *(const float4*)&As[(k + 50) * 36 + r0];
        float4 w = *(const float4*)&Wr[k * HID + n0 + c0];
        float av[4] = {a.x, a.y, a.z, a.w};
        float wv[4] = {w.x, w.y, w.z, w.w};
#pragma unroll
        for (int i = 0; i < 4; ++i)
#pragma unroll
            for (int j = 0; j < 4; ++j) acc[i][j] += av[i] * wv[j];
    }
    float4 bb = *(const float4*)&bias[n0 + c0];
    float bv[4] = {bb.x, bb.y, bb.z, bb.w};
#pragma unroll
    for (int i = 0; i < 4; ++i) {
        int node = m0 + r0 + i;
        if (node < NN) {
            float4 o;
            o.x = fmaxf(acc[i][0] + bv[0], 0.f);
            o.y = fmaxf(acc[i][1] + bv[1], 0.f);
            o.z = fmaxf(acc[i][2] + bv[2], 0.f);
            o.w = fmaxf(acc[i][3] + bv[3], 0.f);
            *(float4*)&h[node * HID + n0 + c0] = o;
        }
    }
}

// ---------------- pad W2 [512,121] -> [512,128] with zeros for aligned float4 streams ----------------

__global__ __launch_bounds__(256) void k_pad(const float* __restrict__ W2l, const float* __restrict__ W2r,
                                             float* __restrict__ Wpl, float* __restrict__ Wpr) {
    int idx = blockIdx.x * 256 + threadIdx.x;
    if (idx < 512 * 128) {
        int r = idx >> 7, c = idx & 127;
        float vl = c < OUTF ? W2l[r * OUTF + c] : 0.f;
        float vr = c < OUTF ? W2r[r * OUTF + c] : 0.f;
        Wpl[idx] = vl;
        Wpr[idx] = vr;
    }
}

// ---------------- GEMM2: P = h @ W2l, Q = h @ W2r  [NN,121] (blockIdx.y selects matrix) ----------------

__global__ __launch_bounds__(256) void k_gemm2(const float* __restrict__ h, const float* __restrict__ Wpl,
                                               const float* __restrict__ Wpr, float* __restrict__ P,
                                               float* __restrict__ Q) {
    __shared__ __align__(16) float As[64 * 36];
    int t = threadIdx.x;
    int m0 = blockIdx.x * 32;
    const float* Wp = blockIdx.y ? Wpr : Wpl;
    float* Out = blockIdx.y ? Q : P;
    int c0 = (t & 31) * 4, r0 = (t >> 5) * 4;
    float acc[4][4] = {};
    for (int kc = 0; kc < HID; kc += 64) {
        for (int idx = t; idx < 2048; idx += 256) {
            int row = idx >> 6, k = idx & 63;
            int node = m0 + row;
            As[k * 36 + row] = node < NN ? h[node * HID + kc + k] : 0.f;
        }
        __syncthreads();
#pragma unroll 4
        for (int k = 0; k < 64; ++k) {
            float4 a = *(const float4*)&As[k * 36 + r0];
            float4 w = *(const float4*)&Wp[(kc + k) * 128 + c0];
            float av[4] = {a.x, a.y, a.z, a.w};
            float wv[4] = {w.x, w.y, w.z, w.w};
#pragma unroll
            for (int i = 0; i < 4; ++i)
#pragma unroll
                for (int j = 0; j < 4; ++j) acc[i][j] += av[i] * wv[j];
        }
        __syncthreads();
    }
#pragma unroll
    for (int i = 0; i < 4; ++i) {
        int node = m0 + r0 + i;
        if (node >= NN) continue;
#pragma unroll
        for (int j = 0; j < 4; ++j) {
            int col = c0 + j;
            if (col < OUTF) Out[node * OUTF + col] = acc[i][j];
        }
    }
}

// ---------------- final: out = mean_agg(P) + Q + b2 ----------------

__global__ __launch_bounds__(128) void k_final(const float* __restrict__ P, const float* __restrict__ Q,
                                               const float* __restrict__ b2, const int* __restrict__ offs,
                                               const int* __restrict__ csr, float* __restrict__ out) {
    int n = blockIdx.x;
    int t = threadIdx.x;
    int b0 = offs[n], b1 = offs[n + 1];
    if (t < OUTF) {
        float s = 0.f;
        for (int i = b0; i < b1; ++i) {
            int sn = csr[i];
            s += P[sn * OUTF + t];
        }
        int dg = b1 - b0;
        float invd = dg > 0 ? 1.f / (float)dg : 1.f;
        out[n * OUTF + t] = s * invd + Q[n * OUTF + t] + b2[t];
    }
}

extern "C" void kernel_launch(void* const* d_in, const int* in_sizes, int n_in,
                              void* d_out, int out_size, void* d_ws, size_t ws_size,
                              hipStream_t stream) {
    const float* x   = (const float*)d_in[0];
    const int* edges = (const int*)d_in[1];
    const float* W1l = (const float*)d_in[2];
    const float* W1r = (const float*)d_in[3];
    const float* b1  = (const float*)d_in[4];
    const float* W2l = (const float*)d_in[5];
    const float* W2r = (const float*)d_in[6];
    const float* b2  = (const float*)d_in[7];
    float* out = (float*)d_out;

    char* ws = (char*)d_ws;
    // workspace layout (all offsets 16B-aligned)
    int* deg    = (int*)(ws + 0);          // 40000 B
    int* cursor = (int*)(ws + 40000);      // 40000 B
    int* offs   = (int*)(ws + 80000);      // 40004 B
    int* csr    = (int*)(ws + 120064);     // 640000 B
    float* A1   = (float*)(ws + 760064);   // 4,000,000 B  [NN,100]
    float* h    = (float*)(ws + 4760064);  // 20,480,000 B [NN,512]
    float* P    = (float*)(ws + 25240064); // 4,840,000 B  [NN,121]
    float* Q    = (float*)(ws + 30080064); // 4,840,000 B  [NN,121]
    float* Wpl  = (float*)(ws + 34920064); // 262,144 B    [512,128]
    float* Wpr  = (float*)(ws + 35182208); // 262,144 B    [512,128]

    const int* srcv = edges;
    const int* dstv = edges + NE;

    hipMemsetAsync(deg, 0, 80000, stream);  // zero deg + cursor (ws is poisoned 0xAA)
    k_count<<<625, 256, 0, stream>>>(dstv, deg);
    k_scan<<<1, 256, 0, stream>>>(deg, offs);
    k_fill<<<625, 256, 0, stream>>>(srcv, dstv, offs, cursor, csr);
    k_pad<<<256, 256, 0, stream>>>(W2l, W2r, Wpl, Wpr);
    k_agg1<<<NN, 64, 0, stream>>>(x, offs, csr, A1);
    k_gemm1<<<dim3(313, 4), 256, 0, stream>>>(A1, W1l, W1r, b1, h);
    k_gemm2<<<dim3(313, 2), 256, 0, stream>>>(h, Wpl, Wpr, P, Q);
    k_final<<<NN, 128, 0, stream>>>(P, Q, b2, offs, csr, out);
}

// Round 3
// 182.137 us; speedup vs baseline: 1.3325x; 1.3325x over previous
//
#include <hip/hip_runtime.h>
#include <hip/hip_bf16.h>

constexpr int NN   = 10000;   // nodes
constexpr int INF  = 50;      // in feats
constexpr int HID  = 512;     // hidden
constexpr int OUTF = 121;     // out feats
constexpr int NE   = 160000;  // edges

typedef __attribute__((ext_vector_type(8))) short short8;
typedef __attribute__((ext_vector_type(4))) float floatx4;

// ---------------- workspace int zeroing (deg + cursor), replaces memset node ----------------

__global__ __launch_bounds__(256) void k_zero(int* __restrict__ p) {
    int i = blockIdx.x * 256 + threadIdx.x;
    if (i < 2 * NN) p[i] = 0;
}

// ---------------- CSR build ----------------

__global__ __launch_bounds__(256) void k_count(const int* __restrict__ dstv, int* __restrict__ deg) {
    int e = blockIdx.x * 256 + threadIdx.x;
    if (e < NE) {
        int d = dstv[e];
        if ((unsigned)d < (unsigned)NN) atomicAdd(&deg[d], 1);
    }
}

__global__ __launch_bounds__(256) void k_scan(const int* __restrict__ deg, int* __restrict__ offs) {
    __shared__ int sums[256];
    int t = threadIdx.x;
    int start = t * 40;
    int end = min(start + 40, NN);
    int s = 0;
    for (int i = start; i < end; ++i) s += deg[i];
    sums[t] = s;
    __syncthreads();
    if (t == 0) {
        int run = 0;
        for (int i = 0; i < 256; ++i) { int v = sums[i]; sums[i] = run; run += v; }
        offs[NN] = run;
    }
    __syncthreads();
    int b = sums[t];
    for (int i = start; i < end; ++i) { offs[i] = b; b += deg[i]; }
}

__global__ __launch_bounds__(256) void k_fill(const int* __restrict__ srcv, const int* __restrict__ dstv,
                                              const int* __restrict__ offs, int* __restrict__ cursor,
                                              int* __restrict__ csr) {
    int e = blockIdx.x * 256 + threadIdx.x;
    if (e < NE) {
        int d = dstv[e];
        if ((unsigned)d < (unsigned)NN) {
            int pos = atomicAdd(&cursor[d], 1);
            int ci = offs[d] + pos;
            if ((unsigned)ci < (unsigned)NE) csr[ci] = srcv[e];  // guard: no wild writes, ever
        }
    }
}

// ---------------- pack weights into MFMA B-fragment order (bf16) ----------------
// B-frag for 16x16x32: lane L holds B[k = kt*32 + (L>>4)*8 + j][n = nt*16 + (L&15)], j=0..7.
// Layout: Bp[((nt*KT + kt)*64 + L)*8 + j] -> each lane's 8 elems contiguous (16B), wave coalesced.

__global__ __launch_bounds__(256) void k_packW(const float* __restrict__ W1l, const float* __restrict__ W1r,
                                               const float* __restrict__ W2l, const float* __restrict__ W2r,
                                               __hip_bfloat16* __restrict__ B1p, __hip_bfloat16* __restrict__ B2p) {
    int idx = blockIdx.x * 256 + threadIdx.x;
    if (idx < 65536) {
        int j = idx & 7, L = (idx >> 3) & 63, kt = (idx >> 9) & 3, nt = idx >> 11;
        int k = kt * 32 + ((L >> 4) * 8 + j);
        int n = nt * 16 + (L & 15);
        float v = (k < 50) ? W1l[k * HID + n] : ((k < 100) ? W1r[(k - 50) * HID + n] : 0.f);
        B1p[idx] = __float2bfloat16(v);
    }
    if (idx < 131072) {
        int j = idx & 7, L = (idx >> 3) & 63, kt = (idx >> 9) & 15, nt = idx >> 13;
        int k = kt * 32 + ((L >> 4) * 8 + j);
        int n = nt * 16 + (L & 15);
        float v;
        if (n < 128) v = (n < OUTF) ? W2l[k * OUTF + n] : 0.f;
        else { int c = n - 128; v = (c < OUTF) ? W2r[k * OUTF + c] : 0.f; }
        B2p[idx] = __float2bfloat16(v);
    }
}

// ---------------- Layer 1 aggregation: A1 = [mean_agg(x) | x | 0pad] bf16 [NN,128] ----------------

__global__ __launch_bounds__(128) void k_agg1(const float* __restrict__ x, const int* __restrict__ offs,
                                              const int* __restrict__ csr, __hip_bfloat16* __restrict__ A1) {
    int n = blockIdx.x;
    int t = threadIdx.x;
    __hip_bfloat16* row = A1 + n * 128;
    if (t < INF) {
        int b0 = offs[n], b1 = offs[n + 1];
        b0 = max(b0, 0); b1 = min(b1, NE);            // guard
        float s = 0.f;
        int cnt = 0;
        for (int i = b0; i < b1; ++i) {
            int sn = csr[i];
            if ((unsigned)sn < (unsigned)NN) {        // guard
                s += x[sn * INF + t];
                ++cnt;
            }
        }
        float invd = (cnt > 0) ? 1.f / (float)cnt : 1.f;
        row[t] = __float2bfloat16(s * invd);
    } else if (t < 100) {
        row[t] = __float2bfloat16(x[n * INF + (t - INF)]);
    } else {
        row[t] = __float2bfloat16(0.f);
    }
}

// ---------------- GEMM1 (MFMA): h = relu(A1 @ W1cat + b1) -> bf16 [NN,512] ----------------
// 256 thr = 4 waves; wave tile 16(M) x 64(N); grid (625, 2). M = 625*16 = 10000 exact.

__global__ __launch_bounds__(256) void k_gemm1(const __hip_bfloat16* __restrict__ A1,
                                               const __hip_bfloat16* __restrict__ B1p,
                                               const float* __restrict__ b1,
                                               __hip_bfloat16* __restrict__ h) {
    int t = threadIdx.x;
    int wave = t >> 6, lane = t & 63;
    int quad = lane >> 4, l16 = lane & 15;
    int m0 = blockIdx.x * 16;
    int n0 = blockIdx.y * 256 + wave * 64;

    const short* Arow = (const short*)A1 + (m0 + l16) * 128 + quad * 8;
    short8 af[4];
#pragma unroll
    for (int ks = 0; ks < 4; ++ks) af[ks] = *(const short8*)(Arow + ks * 32);

    floatx4 zero = {0.f, 0.f, 0.f, 0.f};
    floatx4 acc[4];
#pragma unroll
    for (int nt = 0; nt < 4; ++nt) acc[nt] = zero;

#pragma unroll
    for (int nt = 0; nt < 4; ++nt) {
        int ntile = (n0 >> 4) + nt;
        const short* Bb = (const short*)B1p + ((ntile * 4) * 64 + lane) * 8;
#pragma unroll
        for (int ks = 0; ks < 4; ++ks) {
            short8 bf = *(const short8*)(Bb + ks * 512);
            acc[nt] = __builtin_amdgcn_mfma_f32_16x16x32_bf16(af[ks], bf, acc[nt], 0, 0, 0);
        }
    }

#pragma unroll
    for (int nt = 0; nt < 4; ++nt) {
        int col = n0 + nt * 16 + l16;
        float bias = b1[col];
#pragma unroll
        for (int r = 0; r < 4; ++r) {
            int row = m0 + quad * 4 + r;
            float v = fmaxf(acc[nt][r] + bias, 0.f);
            h[row * HID + col] = __float2bfloat16(v);
        }
    }
}

// ---------------- GEMM2 (MFMA): C = h @ W2cat -> fp32 [NN,256] ----------------
// 256 thr = 4 waves; wave tile 16(M) x 32(N); grid (625, 2) covers N=256.

__global__ __launch_bounds__(256) void k_gemm2(const __hip_bfloat16* __restrict__ h,
                                               const __hip_bfloat16* __restrict__ B2p,
                                               float* __restrict__ C) {
    int t = threadIdx.x;
    int wave = t >> 6, lane = t & 63;
    int quad = lane >> 4, l16 = lane & 15;
    int m0 = blockIdx.x * 16;
    int n0 = blockIdx.y * 128 + wave * 32;

    const short* Arow = (const short*)h + (m0 + l16) * HID + quad * 8;
    int nt0 = n0 >> 4;
    const short* B0 = (const short*)B2p + ((nt0 * 16) * 64 + lane) * 8;
    const short* B1 = (const short*)B2p + (((nt0 + 1) * 16) * 64 + lane) * 8;

    floatx4 acc0 = {0.f, 0.f, 0.f, 0.f};
    floatx4 acc1 = {0.f, 0.f, 0.f, 0.f};

#pragma unroll 4
    for (int ks = 0; ks < 16; ++ks) {
        short8 af = *(const short8*)(Arow + ks * 32);
        short8 bf0 = *(const short8*)(B0 + ks * 512);
        short8 bf1 = *(const short8*)(B1 + ks * 512);
        acc0 = __builtin_amdgcn_mfma_f32_16x16x32_bf16(af, bf0, acc0, 0, 0, 0);
        acc1 = __builtin_amdgcn_mfma_f32_16x16x32_bf16(af, bf1, acc1, 0, 0, 0);
    }

#pragma unroll
    for (int r = 0; r < 4; ++r) {
        int row = m0 + quad * 4 + r;
        C[row * 256 + n0 + l16] = acc0[r];
        C[row * 256 + n0 + 16 + l16] = acc1[r];
    }
}

// ---------------- final: out = mean_agg(C[:,0:121]) + C[:,128:249] + b2 ----------------

__global__ __launch_bounds__(128) void k_final(const float* __restrict__ C, const float* __restrict__ b2,
                                               const int* __restrict__ offs, const int* __restrict__ csr,
                                               float* __restrict__ out) {
    int n = blockIdx.x;
    int t = threadIdx.x;
    if (t >= OUTF) return;
    int b0 = offs[n], b1 = offs[n + 1];
    b0 = max(b0, 0); b1 = min(b1, NE);                // guard
    float s = 0.f;
    int cnt = 0;
    for (int i = b0; i < b1; ++i) {
        int sn = csr[i];
        if ((unsigned)sn < (unsigned)NN) {            // guard
            s += C[sn * 256 + t];
            ++cnt;
        }
    }
    float invd = (cnt > 0) ? 1.f / (float)cnt : 1.f;
    out[n * OUTF + t] = s * invd + C[n * 256 + 128 + t] + b2[t];
}

extern "C" void kernel_launch(void* const* d_in, const int* in_sizes, int n_in,
                              void* d_out, int out_size, void* d_ws, size_t ws_size,
                              hipStream_t stream) {
    const float* x   = (const float*)d_in[0];
    const int* edges = (const int*)d_in[1];
    const float* W1l = (const float*)d_in[2];
    const float* W1r = (const float*)d_in[3];
    const float* b1  = (const float*)d_in[4];
    const float* W2l = (const float*)d_in[5];
    const float* W2r = (const float*)d_in[6];
    const float* b2  = (const float*)d_in[7];
    float* out = (float*)d_out;

    char* ws = (char*)d_ws;
    int* deg    = (int*)(ws + 0);            // 40,000 B   (deg + cursor zeroed by k_zero)
    int* cursor = (int*)(ws + 40000);        // 40,000 B
    int* offs   = (int*)(ws + 80000);        // 40,004 B
    int* csr    = (int*)(ws + 120064);       // 640,000 B
    __hip_bfloat16* A1  = (__hip_bfloat16*)(ws + 760064);    // 2,560,000 B  [NN,128]
    __hip_bfloat16* h   = (__hip_bfloat16*)(ws + 3320064);   // 10,240,000 B [NN,512]
    float* C            = (float*)(ws + 13560064);           // 10,240,000 B [NN,256]
    __hip_bfloat16* B1p = (__hip_bfloat16*)(ws + 23800064);  // 131,072 B
    __hip_bfloat16* B2p = (__hip_bfloat16*)(ws + 23931136);  // 262,144 B

    const int* srcv = edges;
    const int* dstv = edges + NE;

    k_zero<<<79, 256, 0, stream>>>(deg);  // zero deg + cursor (contiguous 2*NN ints)
    k_count<<<625, 256, 0, stream>>>(dstv, deg);
    k_scan<<<1, 256, 0, stream>>>(deg, offs);
    k_fill<<<625, 256, 0, stream>>>(srcv, dstv, offs, cursor, csr);
    k_packW<<<512, 256, 0, stream>>>(W1l, W1r, W2l, W2r, B1p, B2p);
    k_agg1<<<NN, 128, 0, stream>>>(x, offs, csr, A1);
    k_gemm1<<<dim3(625, 2), 256, 0, stream>>>(A1, B1p, b1, h);
    k_gemm2<<<dim3(625, 2), 256, 0, stream>>>(h, B2p, C);
    k_final<<<NN, 128, 0, stream>>>(C, b2, offs, csr, out);
}

// Round 4
// 132.529 us; speedup vs baseline: 1.8313x; 1.3743x over previous
//
#include <hip/hip_runtime.h>
#include <hip/hip_bf16.h>

constexpr int NN   = 10000;   // nodes
constexpr int INF  = 50;      // in feats
constexpr int HID  = 512;     // hidden
constexpr int OUTF = 121;     // out feats
constexpr int NE   = 160000;  // edges
constexpr int DMAX = 64;      // per-node neighbor capacity (Poisson(16): P(deg>64) ~ 1e-19)

typedef __attribute__((ext_vector_type(8))) short short8;
typedef __attribute__((ext_vector_type(4))) float floatx4;

__device__ inline float bf2f(unsigned short u) {
    union { unsigned int i; float f; } v; v.i = ((unsigned)u) << 16; return v.f;
}

// ---------------- prep: zero cursor + pack weights (MFMA B-frag order) + pack xp + A1 self-half ----------------
// grid 512 x 256 = 131072 threads.
// B-frag for 16x16x32: lane L holds B[k = kt*32 + (L>>4)*8 + j][n = nt*16 + (L&15)], j=0..7.
// Bp[((nt*KT + kt)*64 + L)*8 + j]: each lane's 8 elems contiguous (16B), wave coalesced.

__global__ __launch_bounds__(256) void k_prep(const float* __restrict__ x,
                                              const float* __restrict__ W1l, const float* __restrict__ W1r,
                                              const float* __restrict__ W2l, const float* __restrict__ W2r,
                                              int* __restrict__ cursor, __hip_bfloat16* __restrict__ xp,
                                              __hip_bfloat16* __restrict__ A1,
                                              __hip_bfloat16* __restrict__ B1p, __hip_bfloat16* __restrict__ B2p) {
    int idx = blockIdx.x * 256 + threadIdx.x;
    if (idx < NN) cursor[idx] = 0;
    if (idx < 65536) {  // B1p: W1cat[128x512] = vstack(W1l[50], W1r[50], 0[28]); KT=4, NT=32
        int j = idx & 7, L = (idx >> 3) & 63, kt = (idx >> 9) & 3, nt = idx >> 11;
        int k = kt * 32 + ((L >> 4) * 8 + j);
        int n = nt * 16 + (L & 15);
        float v = (k < 50) ? W1l[k * HID + n] : ((k < 100) ? W1r[(k - 50) * HID + n] : 0.f);
        B1p[idx] = __float2bfloat16(v);
    }
    {   // B2p: W2cat[512x256] = [pad128(W2l) | pad128(W2r)]; KT=16, NT=16 (idx < 131072 always)
        int j = idx & 7, L = (idx >> 3) & 63, kt = (idx >> 9) & 15, nt = idx >> 13;
        int k = kt * 32 + ((L >> 4) * 8 + j);
        int n = nt * 16 + (L & 15);
        float v;
        if (n < 128) v = (n < OUTF) ? W2l[k * OUTF + n] : 0.f;
        else { int c = n - 128; v = (c < OUTF) ? W2r[k * OUTF + c] : 0.f; }
        B2p[idx] = __float2bfloat16(v);
    }
    // xp[NN][64] bf16: one-cache-line gather rows (cols >= 50 zero)
    for (int r = idx; r < NN * 64; r += 131072) {
        int n = r >> 6, c = r & 63;
        xp[r] = __float2bfloat16(c < INF ? x[n * INF + c] : 0.f);
    }
    // A1[NN][128] self half: cols 50..99 = x, 100..127 = 0 (cols 0..49 written by k_agg1)
    for (int r = idx; r < NN * 128; r += 131072) {
        int c = r & 127;
        if (c >= 50) {
            int n = r >> 7;
            A1[r] = __float2bfloat16(c < 100 ? x[n * INF + (c - 50)] : 0.f);
        }
    }
}

// ---------------- fixed-capacity CSR fill (no count/scan passes) ----------------

__global__ __launch_bounds__(256) void k_fill(const int* __restrict__ srcv, const int* __restrict__ dstv,
                                              int* __restrict__ cursor, int* __restrict__ csr) {
    int e = blockIdx.x * 256 + threadIdx.x;
    if (e < NE) {
        int d = dstv[e];
        if ((unsigned)d < (unsigned)NN) {
            int pos = atomicAdd(&cursor[d], 1);
            int s = srcv[e];
            s = min(max(s, 0), NN - 1);               // guard: csr always holds valid node ids
            if (pos < DMAX) csr[d * DMAX + pos] = s;
        }
    }
}

// ---------------- layer-1 aggregation: A1[:, 0:50] = mean_agg(xp); one wave per node ----------------

__global__ __launch_bounds__(256) void k_agg1(const __hip_bfloat16* __restrict__ xp,
                                              const int* __restrict__ cursor, const int* __restrict__ csr,
                                              __hip_bfloat16* __restrict__ A1) {
    int lane = threadIdx.x & 63;
    int n = blockIdx.x * 4 + (threadIdx.x >> 6);
    int dt = cursor[n];
    int d = min(dt, DMAX);
    int ids = csr[n * DMAX + lane];                   // whole neighbor list in registers (1 coalesced load)
    const unsigned short* xs = (const unsigned short*)xp;
    float s0 = 0.f, s1 = 0.f, s2 = 0.f, s3 = 0.f;
    int j = 0;
    for (; j + 4 <= d; j += 4) {                      // 4 independent chains -> 4x MLP
        int a = __shfl(ids, j), b = __shfl(ids, j + 1), c = __shfl(ids, j + 2), e = __shfl(ids, j + 3);
        s0 += bf2f(xs[a * 64 + lane]);
        s1 += bf2f(xs[b * 64 + lane]);
        s2 += bf2f(xs[c * 64 + lane]);
        s3 += bf2f(xs[e * 64 + lane]);
    }
    for (; j < d; ++j) {
        int a = __shfl(ids, j);
        s0 += bf2f(xs[a * 64 + lane]);
    }
    float s = (s0 + s1) + (s2 + s3);
    float invd = (dt > 0) ? 1.f / (float)dt : 1.f;
    if (lane < INF) A1[n * 128 + lane] = __float2bfloat16(s * invd);
}

// ---------------- GEMM1 (MFMA): h = relu(A1 @ W1cat + b1) -> bf16 [NN,512] ----------------
// 4 waves; wave tile 16(M) x 64(N); grid (625, 2). M = 625*16 = 10000 exact.

__global__ __launch_bounds__(256) void k_gemm1(const __hip_bfloat16* __restrict__ A1,
                                               const __hip_bfloat16* __restrict__ B1p,
                                               const float* __restrict__ b1,
                                               __hip_bfloat16* __restrict__ h) {
    int t = threadIdx.x;
    int wave = t >> 6, lane = t & 63;
    int quad = lane >> 4, l16 = lane & 15;
    int m0 = blockIdx.x * 16;
    int n0 = blockIdx.y * 256 + wave * 64;

    const short* Arow = (const short*)A1 + (m0 + l16) * 128 + quad * 8;
    short8 af[4];
#pragma unroll
    for (int ks = 0; ks < 4; ++ks) af[ks] = *(const short8*)(Arow + ks * 32);

    floatx4 acc[4];
#pragma unroll
    for (int nt = 0; nt < 4; ++nt) acc[nt] = floatx4{0.f, 0.f, 0.f, 0.f};

#pragma unroll
    for (int nt = 0; nt < 4; ++nt) {
        int ntile = (n0 >> 4) + nt;
        const short* Bb = (const short*)B1p + ((ntile * 4) * 64 + lane) * 8;
#pragma unroll
        for (int ks = 0; ks < 4; ++ks) {
            short8 bf = *(const short8*)(Bb + ks * 512);
            acc[nt] = __builtin_amdgcn_mfma_f32_16x16x32_bf16(af[ks], bf, acc[nt], 0, 0, 0);
        }
    }

#pragma unroll
    for (int nt = 0; nt < 4; ++nt) {
        int col = n0 + nt * 16 + l16;
        float bias = b1[col];
#pragma unroll
        for (int r = 0; r < 4; ++r) {
            int row = m0 + quad * 4 + r;
            float v = fmaxf(acc[nt][r] + bias, 0.f);
            h[row * HID + col] = __float2bfloat16(v);
        }
    }
}

// ---------------- GEMM2 (MFMA): Pb = bf16(h @ W2l_pad) [NN,128], Q = fp32(h @ W2r_pad) [NN,128] ----------------
// 4 waves; wave tile 16(M) x 32(N); grid (625, 2): y=0 -> Pb, y=1 -> Q.

__global__ __launch_bounds__(256) void k_gemm2(const __hip_bfloat16* __restrict__ h,
                                               const __hip_bfloat16* __restrict__ B2p,
                                               __hip_bfloat16* __restrict__ Pb,
                                               float* __restrict__ Q) {
    int t = threadIdx.x;
    int wave = t >> 6, lane = t & 63;
    int quad = lane >> 4, l16 = lane & 15;
    int m0 = blockIdx.x * 16;
    int nloc = wave * 32;                              // local col within the 128-wide half
    int nt0 = (blockIdx.y * 128 + nloc) >> 4;          // global B tile index

    const short* Arow = (const short*)h + (m0 + l16) * HID + quad * 8;
    const short* B0 = (const short*)B2p + ((nt0 * 16) * 64 + lane) * 8;
    const short* B1 = (const short*)B2p + (((nt0 + 1) * 16) * 64 + lane) * 8;

    floatx4 acc0 = {0.f, 0.f, 0.f, 0.f};
    floatx4 acc1 = {0.f, 0.f, 0.f, 0.f};

#pragma unroll 4
    for (int ks = 0; ks < 16; ++ks) {
        short8 af = *(const short8*)(Arow + ks * 32);
        short8 bf0 = *(const short8*)(B0 + ks * 512);
        short8 bf1 = *(const short8*)(B1 + ks * 512);
        acc0 = __builtin_amdgcn_mfma_f32_16x16x32_bf16(af, bf0, acc0, 0, 0, 0);
        acc1 = __builtin_amdgcn_mfma_f32_16x16x32_bf16(af, bf1, acc1, 0, 0, 0);
    }

    if (blockIdx.y == 0) {
#pragma unroll
        for (int r = 0; r < 4; ++r) {
            int row = m0 + quad * 4 + r;
            Pb[row * 128 + nloc + l16]      = __float2bfloat16(acc0[r]);
            Pb[row * 128 + nloc + 16 + l16] = __float2bfloat16(acc1[r]);
        }
    } else {
#pragma unroll
        for (int r = 0; r < 4; ++r) {
            int row = m0 + quad * 4 + r;
            Q[row * 128 + nloc + l16]      = acc0[r];
            Q[row * 128 + nloc + 16 + l16] = acc1[r];
        }
    }
}

// ---------------- final: out = mean_agg(Pb)[:, :121] + Q[:, :121] + b2; one wave per node ----------------

__global__ __launch_bounds__(256) void k_final(const __hip_bfloat16* __restrict__ Pb,
                                               const float* __restrict__ Q, const float* __restrict__ b2,
                                               const int* __restrict__ cursor, const int* __restrict__ csr,
                                               float* __restrict__ out) {
    int lane = threadIdx.x & 63;
    int n = blockIdx.x * 4 + (threadIdx.x >> 6);
    int dt = cursor[n];
    int d = min(dt, DMAX);
    int ids = csr[n * DMAX + lane];
    const unsigned* Pw = (const unsigned*)Pb;          // 2 bf16 cols per 4B word; lane owns cols 2t, 2t+1
    float lo0 = 0.f, lo1 = 0.f, lo2 = 0.f, lo3 = 0.f;
    float hi0 = 0.f, hi1 = 0.f, hi2 = 0.f, hi3 = 0.f;
    int j = 0;
    for (; j + 4 <= d; j += 4) {
        int a = __shfl(ids, j), b = __shfl(ids, j + 1), c = __shfl(ids, j + 2), e = __shfl(ids, j + 3);
        unsigned w0 = Pw[a * 64 + lane];
        unsigned w1 = Pw[b * 64 + lane];
        unsigned w2 = Pw[c * 64 + lane];
        unsigned w3 = Pw[e * 64 + lane];
        lo0 += __uint_as_float(w0 << 16); hi0 += __uint_as_float(w0 & 0xffff0000u);
        lo1 += __uint_as_float(w1 << 16); hi1 += __uint_as_float(w1 & 0xffff0000u);
        lo2 += __uint_as_float(w2 << 16); hi2 += __uint_as_float(w2 & 0xffff0000u);
        lo3 += __uint_as_float(w3 << 16); hi3 += __uint_as_float(w3 & 0xffff0000u);
    }
    for (; j < d; ++j) {
        int a = __shfl(ids, j);
        unsigned w0 = Pw[a * 64 + lane];
        lo0 += __uint_as_float(w0 << 16); hi0 += __uint_as_float(w0 & 0xffff0000u);
    }
    float slo = (lo0 + lo1) + (lo2 + lo3);
    float shi = (hi0 + hi1) + (hi2 + hi3);
    float invd = (dt > 0) ? 1.f / (float)dt : 1.f;
    int c0 = lane * 2, c1 = lane * 2 + 1;
    if (c0 < OUTF) out[n * OUTF + c0] = slo * invd + Q[n * 128 + c0] + b2[c0];
    if (c1 < OUTF) out[n * OUTF + c1] = shi * invd + Q[n * 128 + c1] + b2[c1];
}

extern "C" void kernel_launch(void* const* d_in, const int* in_sizes, int n_in,
                              void* d_out, int out_size, void* d_ws, size_t ws_size,
                              hipStream_t stream) {
    const float* x   = (const float*)d_in[0];
    const int* edges = (const int*)d_in[1];
    const float* W1l = (const float*)d_in[2];
    const float* W1r = (const float*)d_in[3];
    const float* b1  = (const float*)d_in[4];
    const float* W2l = (const float*)d_in[5];
    const float* W2r = (const float*)d_in[6];
    const float* b2  = (const float*)d_in[7];
    float* out = (float*)d_out;

    char* ws = (char*)d_ws;
    int* cursor         = (int*)(ws + 0);                    // 40,000 B
    int* csr            = (int*)(ws + 40000);                // 2,560,000 B  [NN,64]
    __hip_bfloat16* xp  = (__hip_bfloat16*)(ws + 2600000);   // 1,280,000 B  [NN,64]
    __hip_bfloat16* A1  = (__hip_bfloat16*)(ws + 3880000);   // 2,560,000 B  [NN,128]
    __hip_bfloat16* h   = (__hip_bfloat16*)(ws + 6440000);   // 10,240,000 B [NN,512]
    __hip_bfloat16* Pb  = (__hip_bfloat16*)(ws + 16680000);  // 2,560,000 B  [NN,128]
    float* Q            = (float*)(ws + 19240000);           // 5,120,000 B  [NN,128]
    __hip_bfloat16* B1p = (__hip_bfloat16*)(ws + 24360000);  // 131,072 B
    __hip_bfloat16* B2p = (__hip_bfloat16*)(ws + 24491072);  // 262,144 B

    const int* srcv = edges;
    const int* dstv = edges + NE;

    k_prep<<<512, 256, 0, stream>>>(x, W1l, W1r, W2l, W2r, cursor, xp, A1, B1p, B2p);
    k_fill<<<625, 256, 0, stream>>>(srcv, dstv, cursor, csr);
    k_agg1<<<2500, 256, 0, stream>>>(xp, cursor, csr, A1);
    k_gemm1<<<dim3(625, 2), 256, 0, stream>>>(A1, B1p, b1, h);
    k_gemm2<<<dim3(625, 2), 256, 0, stream>>>(h, B2p, Pb, Q);
    k_final<<<2500, 256, 0, stream>>>(Pb, Q, b2, cursor, csr, out);
}

// Round 5
// 127.416 us; speedup vs baseline: 1.9048x; 1.0401x over previous
//
#include <hip/hip_runtime.h>
#include <hip/hip_bf16.h>

constexpr int NN   = 10000;   // nodes
constexpr int INF  = 50;      // in feats
constexpr int HID  = 512;     // hidden
constexpr int OUTF = 121;     // out feats
constexpr int NE   = 160000;  // edges
constexpr int DMAX = 64;      // per-node neighbor capacity (Poisson(16): P(deg>64) ~ 1e-19)

typedef __attribute__((ext_vector_type(8))) short short8;
typedef __attribute__((ext_vector_type(4))) float floatx4;

__device__ inline float bf2f(unsigned short u) {
    union { unsigned int i; float f; } v; v.i = ((unsigned)u) << 16; return v.f;
}
__device__ inline unsigned short f2bf(float f) {
    __hip_bfloat16 h = __float2bfloat16(f);
    return *(unsigned short*)&h;
}

// ---------------- prep: zero cursor + pack weights (MFMA B-frag order) + pack xp ----------------
// grid 512 x 256 = 131072 threads.
// B-frag for 16x16x32: lane L holds B[k = kt*32 + (L>>4)*8 + j][n = nt*16 + (L&15)], j=0..7.
// Bp[((nt*KT + kt)*64 + L)*8 + j]: each lane's 8 elems contiguous (16B), wave coalesced.

__global__ __launch_bounds__(256) void k_prep(const float* __restrict__ x,
                                              const float* __restrict__ W1l, const float* __restrict__ W1r,
                                              const float* __restrict__ W2l, const float* __restrict__ W2r,
                                              int* __restrict__ cursor, __hip_bfloat16* __restrict__ xp,
                                              __hip_bfloat16* __restrict__ B1p, __hip_bfloat16* __restrict__ B2p) {
    int idx = blockIdx.x * 256 + threadIdx.x;
    if (idx < NN) cursor[idx] = 0;
    if (idx < 65536) {  // B1p: W1cat[128x512] = vstack(W1l[50], W1r[50], 0[28]); KT=4, NT=32
        int j = idx & 7, L = (idx >> 3) & 63, kt = (idx >> 9) & 3, nt = idx >> 11;
        int k = kt * 32 + ((L >> 4) * 8 + j);
        int n = nt * 16 + (L & 15);
        float v = (k < 50) ? W1l[k * HID + n] : ((k < 100) ? W1r[(k - 50) * HID + n] : 0.f);
        B1p[idx] = __float2bfloat16(v);
    }
    {   // B2p: W2cat[512x256] = [pad128(W2l) | pad128(W2r)]; KT=16, NT=16 (idx < 131072 always)
        int j = idx & 7, L = (idx >> 3) & 63, kt = (idx >> 9) & 15, nt = idx >> 13;
        int k = kt * 32 + ((L >> 4) * 8 + j);
        int n = nt * 16 + (L & 15);
        float v;
        if (n < 128) v = (n < OUTF) ? W2l[k * OUTF + n] : 0.f;
        else { int c = n - 128; v = (c < OUTF) ? W2r[k * OUTF + c] : 0.f; }
        B2p[idx] = __float2bfloat16(v);
    }
    // xp[NN][64] bf16: one-cache-line gather rows (cols >= 50 zero)
    for (int r = idx; r < NN * 64; r += 131072) {
        int n = r >> 6, c = r & 63;
        xp[r] = __float2bfloat16(c < INF ? x[n * INF + c] : 0.f);
    }
}

// ---------------- fixed-capacity CSR fill (no count/scan passes) ----------------

__global__ __launch_bounds__(256) void k_fill(const int* __restrict__ srcv, const int* __restrict__ dstv,
                                              int* __restrict__ cursor, int* __restrict__ csr) {
    int e = blockIdx.x * 256 + threadIdx.x;
    if (e < NE) {
        int d = dstv[e];
        if ((unsigned)d < (unsigned)NN) {
            int pos = atomicAdd(&cursor[d], 1);
            int s = srcv[e];
            s = min(max(s, 0), NN - 1);               // guard: csr always holds valid node ids
            if (pos < DMAX) csr[d * DMAX + pos] = s;
        }
    }
}

// ---------------- fused agg1 + GEMM1 + GEMM2: 16 nodes per block, everything via LDS ----------------
// Phase A: gather mean_agg(xp) + self into As[16][136] (bf16, row-pad for b128 reads)
// Phase B: h_tile = relu(As @ W1cat + b1) -> Ht[16][520] (bf16)
// Phase C: Pb = bf16(h @ W2l_pad), Q = fp32(h @ W2r_pad); waves 0,1 -> Pb, waves 2,3 -> Q

__global__ __launch_bounds__(256) void k_fused(const __hip_bfloat16* __restrict__ xp,
                                               const int* __restrict__ cursor, const int* __restrict__ csr,
                                               const __hip_bfloat16* __restrict__ B1p,
                                               const float* __restrict__ b1,
                                               const __hip_bfloat16* __restrict__ B2p,
                                               __hip_bfloat16* __restrict__ Pb, float* __restrict__ Q) {
    __shared__ __align__(16) unsigned short As[16 * 136];
    __shared__ __align__(16) unsigned short Ht[16 * 520];
    int t = threadIdx.x;
    int w = t >> 6, lane = t & 63, quad = lane >> 4, l16 = lane & 15;
    int m0 = blockIdx.x * 16;
    const unsigned short* xs = (const unsigned short*)xp;

    // ---- phase A: wave w handles nodes m0 + w*4 .. +3 ----
#pragma unroll
    for (int p = 0; p < 4; ++p) {
        int nl = w * 4 + p, n = m0 + nl;
        int dt = cursor[n];
        int d = min(dt, DMAX);
        int ids = csr[n * DMAX + lane];               // whole neighbor list in registers
        float s0 = 0.f, s1 = 0.f, s2 = 0.f, s3 = 0.f;
        int j = 0;
        for (; j + 4 <= d; j += 4) {                  // 4 independent chains -> 4x MLP
            int a = __shfl(ids, j), b = __shfl(ids, j + 1), c = __shfl(ids, j + 2), e = __shfl(ids, j + 3);
            s0 += bf2f(xs[a * 64 + lane]);
            s1 += bf2f(xs[b * 64 + lane]);
            s2 += bf2f(xs[c * 64 + lane]);
            s3 += bf2f(xs[e * 64 + lane]);
        }
        for (; j < d; ++j) {
            int a = __shfl(ids, j);
            s0 += bf2f(xs[a * 64 + lane]);
        }
        float s = (s0 + s1) + (s2 + s3);
        float invd = (dt > 0) ? 1.f / (float)dt : 1.f;
        unsigned short self = xs[n * 64 + lane];      // cols 0..49 feats, 50..63 zero
        if (lane < INF) As[nl * 136 + lane] = f2bf(s * invd);
        As[nl * 136 + 50 + lane] = self;              // cols 50..113 (100..113 get zeros)
        if (lane < 7) *(unsigned*)&As[nl * 136 + 114 + 2 * lane] = 0u;  // cols 114..127
    }
    __syncthreads();

    // ---- phase B: wave w covers cols w*128 .. +127 of h ----
    short8 af[4];
#pragma unroll
    for (int ks = 0; ks < 4; ++ks) af[ks] = *(const short8*)&As[l16 * 136 + ks * 32 + quad * 8];
    {
        floatx4 acc[8];
#pragma unroll
        for (int nt = 0; nt < 8; ++nt) acc[nt] = floatx4{0.f, 0.f, 0.f, 0.f};
#pragma unroll
        for (int nt = 0; nt < 8; ++nt) {
            int ntile = w * 8 + nt;
            const short* Bb = (const short*)B1p + (ntile * 4 * 64 + lane) * 8;
#pragma unroll
            for (int ks = 0; ks < 4; ++ks) {
                short8 bf = *(const short8*)(Bb + ks * 512);
                acc[nt] = __builtin_amdgcn_mfma_f32_16x16x32_bf16(af[ks], bf, acc[nt], 0, 0, 0);
            }
        }
#pragma unroll
        for (int nt = 0; nt < 8; ++nt) {
            int col = w * 128 + nt * 16 + l16;
            float bias = b1[col];
#pragma unroll
            for (int r = 0; r < 4; ++r)
                Ht[(quad * 4 + r) * 520 + col] = f2bf(fmaxf(acc[nt][r] + bias, 0.f));
        }
    }
    __syncthreads();

    // ---- phase C: waves 0,1 -> Pb cols 0..127; waves 2,3 -> Q cols 0..127 ----
    int isQ = w >> 1;
    int halfcol = (w & 1) * 64;
    int tbase = isQ * 8 + (w & 1) * 4;                // B2p 16-col tile base
    floatx4 acc[4];
#pragma unroll
    for (int nt = 0; nt < 4; ++nt) acc[nt] = floatx4{0.f, 0.f, 0.f, 0.f};
#pragma unroll 4
    for (int ks = 0; ks < 16; ++ks) {
        short8 a2 = *(const short8*)&Ht[l16 * 520 + ks * 32 + quad * 8];
#pragma unroll
        for (int nt = 0; nt < 4; ++nt) {
            const short* Bb = (const short*)B2p + (((tbase + nt) * 16 + ks) * 64 + lane) * 8;
            short8 bf = *(const short8*)Bb;
            acc[nt] = __builtin_amdgcn_mfma_f32_16x16x32_bf16(a2, bf, acc[nt], 0, 0, 0);
        }
    }
    if (!isQ) {
#pragma unroll
        for (int nt = 0; nt < 4; ++nt)
#pragma unroll
            for (int r = 0; r < 4; ++r) {
                int row = m0 + quad * 4 + r;
                Pb[row * 128 + halfcol + nt * 16 + l16] = __float2bfloat16(acc[nt][r]);
            }
    } else {
#pragma unroll
        for (int nt = 0; nt < 4; ++nt)
#pragma unroll
            for (int r = 0; r < 4; ++r) {
                int row = m0 + quad * 4 + r;
                Q[row * 128 + halfcol + nt * 16 + l16] = acc[nt][r];
            }
    }
}

// ---------------- final: out = mean_agg(Pb)[:, :121] + Q[:, :121] + b2; one wave per node ----------------

__global__ __launch_bounds__(256) void k_final(const __hip_bfloat16* __restrict__ Pb,
                                               const float* __restrict__ Q, const float* __restrict__ b2,
                                               const int* __restrict__ cursor, const int* __restrict__ csr,
                                               float* __restrict__ out) {
    int lane = threadIdx.x & 63;
    int n = blockIdx.x * 4 + (threadIdx.x >> 6);
    int dt = cursor[n];
    int d = min(dt, DMAX);
    int ids = csr[n * DMAX + lane];
    const unsigned* Pw = (const unsigned*)Pb;          // 2 bf16 cols per 4B word; lane owns cols 2t, 2t+1
    float lo0 = 0.f, lo1 = 0.f, lo2 = 0.f, lo3 = 0.f;
    float hi0 = 0.f, hi1 = 0.f, hi2 = 0.f, hi3 = 0.f;
    int j = 0;
    for (; j + 4 <= d; j += 4) {
        int a = __shfl(ids, j), b = __shfl(ids, j + 1), c = __shfl(ids, j + 2), e = __shfl(ids, j + 3);
        unsigned w0 = Pw[a * 64 + lane];
        unsigned w1 = Pw[b * 64 + lane];
        unsigned w2 = Pw[c * 64 + lane];
        unsigned w3 = Pw[e * 64 + lane];
        lo0 += __uint_as_float(w0 << 16); hi0 += __uint_as_float(w0 & 0xffff0000u);
        lo1 += __uint_as_float(w1 << 16); hi1 += __uint_as_float(w1 & 0xffff0000u);
        lo2 += __uint_as_float(w2 << 16); hi2 += __uint_as_float(w2 & 0xffff0000u);
        lo3 += __uint_as_float(w3 << 16); hi3 += __uint_as_float(w3 & 0xffff0000u);
    }
    for (; j < d; ++j) {
        int a = __shfl(ids, j);
        unsigned w0 = Pw[a * 64 + lane];
        lo0 += __uint_as_float(w0 << 16); hi0 += __uint_as_float(w0 & 0xffff0000u);
    }
    float slo = (lo0 + lo1) + (lo2 + lo3);
    float shi = (hi0 + hi1) + (hi2 + hi3);
    float invd = (dt > 0) ? 1.f / (float)dt : 1.f;
    int c0 = lane * 2, c1 = lane * 2 + 1;
    if (c0 < OUTF) out[n * OUTF + c0] = slo * invd + Q[n * 128 + c0] + b2[c0];
    if (c1 < OUTF) out[n * OUTF + c1] = shi * invd + Q[n * 128 + c1] + b2[c1];
}

extern "C" void kernel_launch(void* const* d_in, const int* in_sizes, int n_in,
                              void* d_out, int out_size, void* d_ws, size_t ws_size,
                              hipStream_t stream) {
    const float* x   = (const float*)d_in[0];
    const int* edges = (const int*)d_in[1];
    const float* W1l = (const float*)d_in[2];
    const float* W1r = (const float*)d_in[3];
    const float* b1  = (const float*)d_in[4];
    const float* W2l = (const float*)d_in[5];
    const float* W2r = (const float*)d_in[6];
    const float* b2  = (const float*)d_in[7];
    float* out = (float*)d_out;

    char* ws = (char*)d_ws;
    int* cursor         = (int*)(ws + 0);                    // 40,000 B
    int* csr            = (int*)(ws + 40000);                // 2,560,000 B [NN,64]
    __hip_bfloat16* xp  = (__hip_bfloat16*)(ws + 2600000);   // 1,280,000 B [NN,64]
    __hip_bfloat16* Pb  = (__hip_bfloat16*)(ws + 3880000);   // 2,560,000 B [NN,128]
    float* Q            = (float*)(ws + 6440000);            // 5,120,000 B [NN,128]
    __hip_bfloat16* B1p = (__hip_bfloat16*)(ws + 11560000);  // 131,072 B
    __hip_bfloat16* B2p = (__hip_bfloat16*)(ws + 11691072);  // 262,144 B

    const int* srcv = edges;
    const int* dstv = edges + NE;

    k_prep<<<512, 256, 0, stream>>>(x, W1l, W1r, W2l, W2r, cursor, xp, B1p, B2p);
    k_fill<<<625, 256, 0, stream>>>(srcv, dstv, cursor, csr);
    k_fused<<<625, 256, 0, stream>>>(xp, cursor, csr, B1p, b1, B2p, Pb, Q);
    k_final<<<2500, 256, 0, stream>>>(Pb, Q, b2, cursor, csr, out);
}